// Round 5
// baseline (1561.701 us; speedup 1.0000x reference)
//
#include <hip/hip_runtime.h>

// GNN encoder + GRU message-passing decoder, FULLY FUSED single kernel.
// Insight: all ops are batch-local (32 nodes/batch, fully-connected graph),
// so one block = one batch runs encoder + 2 passing rounds + 25 GRU steps
// with only __syncthreads() -- kills the 82-launch structure (R4: 1105us
// smeared over latency-bound small kernels).
//
// All GEMMs: mfma_f32_16x16x32_f16, fp32 accumulate. Weights converted to
// fp16 (transposed, k-contiguous) once per call. Edge w2T cached in LDS
// (reused 32x/step). GRU gates packed into one [512 x 288] B matrix:
// j-groups = {rs, is, ns(ni part), hn(h part)}, k = [msg(128)|h(128)|dec(3)|pad].

#define NJ 32
#define ROWS 512
#define TSTEPS 25

typedef _Float16 half_t;
typedef __attribute__((ext_vector_type(8))) _Float16 half8;
typedef __attribute__((ext_vector_type(8))) short short8;
typedef __attribute__((ext_vector_type(4))) float f32x4;

// fp16 converted-weight pool (halves). All offsets multiple of 8 (16B align).
#define OFF_ENC_W1T 0          // [256 j][160 k]  (k>=150 zero)
#define OFF_ENC_W2T 40960      // [128 j][256 k]
#define OFF_PE_W1T  73728      // [512 j][128 k]  (j<256: P, j>=256: Q)
#define OFF_PE_W2T  139264     // [128 j][256 k]
#define OFF_PN_W1T  172032     // [256 j][128 k]
#define OFF_PN_W2T  204800     // [128 j][256 k]
#define OFF_DE_W1T  237568     // [512 j][128 k]
#define OFF_DE_W2T  303104     // [128 j][256 k]
#define OFF_WGT     335872     // [512 j][288 k]
#define WTOTAL      483328

__device__ __align__(16) half_t g_wf16[WTOTAL];

__device__ __forceinline__ half8 h8zero() {
    half8 z;
    #pragma unroll
    for (int e = 0; e < 8; ++e) z[e] = (half_t)0.f;
    return z;
}

__device__ __forceinline__ half8 relu8(half8 x) {
    short8 s = *(short8*)&x;
    short8 m = s >> 15;         // -1 where negative
    s = s & ~m;                 // zero negatives (and -0)
    return *(half8*)&s;
}

__device__ __forceinline__ half8 frag_from_f32(const float* base) {
    f32x4 a = *(const f32x4*)base;
    f32x4 c = *(const f32x4*)(base + 4);
    half8 h;
    #pragma unroll
    for (int e = 0; e < 4; ++e) { h[e] = (half_t)a[e]; h[4 + e] = (half_t)c[e]; }
    return h;
}

// ---------------- fp32 -> fp16 transposed weight conversion -----------------
__global__ void convert_kernel(const float* __restrict__ enc_w1, const float* __restrict__ enc_w2,
                               const float* __restrict__ pe_w1, const float* __restrict__ pe_w2,
                               const float* __restrict__ pn_w1, const float* __restrict__ pn_w2,
                               const float* __restrict__ de_w1, const float* __restrict__ de_w2,
                               const float* __restrict__ w_hr, const float* __restrict__ w_hi,
                               const float* __restrict__ w_hn, const float* __restrict__ w_ir,
                               const float* __restrict__ w_ii, const float* __restrict__ w_in) {
    const int idx = blockIdx.x * 256 + threadIdx.x;
    if (idx >= WTOTAL) return;
    float v = 0.f;
    if (idx < OFF_ENC_W2T) {
        int o = idx, j = o / 160, k = o - j * 160;
        v = (k < 150) ? enc_w1[k * 256 + j] : 0.f;
    } else if (idx < OFF_PE_W1T) {
        int o = idx - OFF_ENC_W2T, j = o >> 8, k = o & 255;
        v = enc_w2[k * 128 + j];
    } else if (idx < OFF_PE_W2T) {
        int o = idx - OFF_PE_W1T, j = o >> 7, k = o & 127;
        v = pe_w1[(k + ((j >= 256) ? 128 : 0)) * 256 + (j & 255)];
    } else if (idx < OFF_PN_W1T) {
        int o = idx - OFF_PE_W2T, j = o >> 8, k = o & 255;
        v = pe_w2[k * 128 + j];
    } else if (idx < OFF_PN_W2T) {
        int o = idx - OFF_PN_W1T, j = o >> 7, k = o & 127;
        v = pn_w1[k * 256 + j];
    } else if (idx < OFF_DE_W1T) {
        int o = idx - OFF_PN_W2T, j = o >> 8, k = o & 255;
        v = pn_w2[k * 128 + j];
    } else if (idx < OFF_DE_W2T) {
        int o = idx - OFF_DE_W1T, j = o >> 7, k = o & 127;
        v = de_w1[(k + ((j >= 256) ? 128 : 0)) * 256 + (j & 255)];
    } else if (idx < OFF_WGT) {
        int o = idx - OFF_DE_W2T, j = o >> 8, k = o & 255;
        v = de_w2[k * 128 + j];
    } else {
        int o = idx - OFF_WGT, j = o / 288, k = o - j * 288;
        int g = j >> 7, jj = j & 127;
        if (g == 0)
            v = (k < 128) ? w_ir[k * 128 + jj] : (k < 256) ? w_hr[(k - 128) * 128 + jj]
              : (k < 259) ? w_ir[(128 + k - 256) * 128 + jj] : 0.f;
        else if (g == 1)
            v = (k < 128) ? w_ii[k * 128 + jj] : (k < 256) ? w_hi[(k - 128) * 128 + jj]
              : (k < 259) ? w_ii[(128 + k - 256) * 128 + jj] : 0.f;
        else if (g == 2)
            v = (k < 128) ? w_in[k * 128 + jj]
              : (k >= 256 && k < 259) ? w_in[(128 + k - 256) * 128 + jj] : 0.f;
        else
            v = (k >= 128 && k < 256) ? w_hn[(k - 128) * 128 + jj] : 0.f;
    }
    g_wf16[idx] = (half_t)v;
}

// ================= device helpers for the fused kernel =================
// MFMA fragment layouts (verified in R4 with bf16; dtype-independent):
//   A[m][k]: m = lane&15, k = quad*8 + i (8 contiguous k per lane)
//   B[k][n]: n = lane&15, k = quad*8 + i (wT[j][k] row = n, k contiguous)
//   D[m][n]: n = lane&15, m = quad*4 + reg

// layer1 of a row-MLP: hid[32][264] (fp16, relu, +b1). N=256. 4 tasks/wave.
template <int ASRC>  // 0: half src stride 168 (encin); 1: f32 src stride 128 (msg)
__device__ __forceinline__ void mlp_l1(const half_t* Ah, const float* Af,
                                       const half_t* Bt, int bstride, int ksteps,
                                       const float* b1g, half_t* hid,
                                       int wave, int m16, int quad) {
    #pragma unroll
    for (int i = 0; i < 4; ++i) {
        const int tau = wave + i * 8;
        const int nt = tau & 15, mt = tau >> 4;
        f32x4 acc = (f32x4)(0.f);
        for (int k = 0; k < ksteps; ++k) {
            const int row = mt * 16 + m16, kk = k * 32 + quad * 8;
            half8 a = (ASRC == 0) ? *(const half8*)&Ah[row * 168 + kk]
                                  : frag_from_f32(&Af[row * 128 + kk]);
            half8 bf = *(const half8*)&Bt[(nt * 16 + m16) * bstride + kk];
            acc = __builtin_amdgcn_mfma_f32_16x16x32_f16(a, bf, acc, 0, 0, 0);
        }
        const int j = nt * 16 + m16;
        const float bj = b1g[j];
        #pragma unroll
        for (int g = 0; g < 4; ++g) {
            const int s = mt * 16 + quad * 4 + g;
            hid[s * 264 + j] = (half_t)fmaxf(acc[g] + bj, 0.f);
        }
    }
}

// layer2: x[32][128] fp32 = relu(hid @ w2 + b2). K=256, N=128. 2 tasks/wave.
__device__ __forceinline__ void mlp_l2(const half_t* hid, const half_t* Bt,
                                       const float* b2g, float* xout,
                                       int wave, int m16, int quad) {
    #pragma unroll
    for (int i = 0; i < 2; ++i) {
        const int tau = wave + i * 8;
        const int nt = tau & 7, mt = tau >> 3;
        f32x4 acc = (f32x4)(0.f);
        #pragma unroll
        for (int k = 0; k < 8; ++k) {
            const int kk = k * 32 + quad * 8;
            half8 a = *(const half8*)&hid[(mt * 16 + m16) * 264 + kk];
            half8 bf = *(const half8*)&Bt[(nt * 16 + m16) * 256 + kk];
            acc = __builtin_amdgcn_mfma_f32_16x16x32_f16(a, bf, acc, 0, 0, 0);
        }
        const int j = nt * 16 + m16;
        const float bj = b2g[j];
        #pragma unroll
        for (int g = 0; g < 4; ++g) {
            const int s = mt * 16 + quad * 4 + g;
            xout[s * 128 + j] = fmaxf(acc[g] + bj, 0.f);
        }
    }
}

// P,Qb projections: [32 x 128] @ w1T[512 x 128]. 8 tasks/wave.
__device__ __forceinline__ void pq_phase(const float* h, const half_t* w1T,
                                         const float* b1g, half_t* P, half_t* Qb,
                                         int wave, int m16, int quad) {
    half8 afr[4];
    #pragma unroll
    for (int ti = 0; ti < 8; ++ti) {
        const int tau = wave + ti * 8;
        const int nt = tau & 31, mt = tau >> 5;
        if ((ti & 3) == 0) {
            #pragma unroll
            for (int k = 0; k < 4; ++k)
                afr[k] = frag_from_f32(&h[(mt * 16 + m16) * 128 + k * 32 + quad * 8]);
        }
        f32x4 acc = (f32x4)(0.f);
        #pragma unroll
        for (int k = 0; k < 4; ++k) {
            half8 bf = *(const half8*)&w1T[(nt * 16 + m16) * 128 + k * 32 + quad * 8];
            acc = __builtin_amdgcn_mfma_f32_16x16x32_f16(afr[k], bf, acc, 0, 0, 0);
        }
        const int j = nt * 16 + m16;
        if (j < 256) {
            #pragma unroll
            for (int g = 0; g < 4; ++g)
                P[(mt * 16 + quad * 4 + g) * 264 + j] = (half_t)acc[g];
        } else {
            const float bj = b1g[j - 256];
            #pragma unroll
            for (int g = 0; g < 4; ++g)
                Qb[(mt * 16 + quad * 4 + g) * 264 + (j - 256)] = (half_t)(acc[g] + bj);
        }
    }
}

// edge layer2 + relu + mean over senders. wave handles r = wave*4 .. wave*4+3.
__device__ __forceinline__ void edge_phase(const half_t* P, const half_t* Qb,
                                           const half_t* w2T, const float* b2g,
                                           float* msg, int wave, int m16, int quad) {
    float b2n[8];
    #pragma unroll
    for (int n = 0; n < 8; ++n) b2n[n] = b2g[n * 16 + m16];
    #pragma unroll
    for (int pr = 0; pr < 2; ++pr) {
        const int r0 = wave * 4 + pr * 2;
        half8 A[2][2][8];                      // [ri][mtile][k] = 128 VGPR
        #pragma unroll
        for (int ri = 0; ri < 2; ++ri) {
            const int r = r0 + ri;
            half8 qb[8];
            #pragma unroll
            for (int k = 0; k < 8; ++k)
                qb[k] = *(const half8*)&Qb[r * 264 + k * 32 + quad * 8];
            #pragma unroll
            for (int mt = 0; mt < 2; ++mt) {
                const int s = mt * 16 + m16;
                const bool dz = (s == r);       // diagonal row zeroed
                #pragma unroll
                for (int k = 0; k < 8; ++k) {
                    half8 pv = *(const half8*)&P[s * 264 + k * 32 + quad * 8];
                    half8 hv = relu8(pv + qb[k]);
                    A[ri][mt][k] = dz ? h8zero() : hv;
                }
            }
        }
        #pragma unroll
        for (int n = 0; n < 8; ++n) {
            half8 Bf[8];
            #pragma unroll
            for (int k = 0; k < 8; ++k)
                Bf[k] = *(const half8*)&w2T[(n * 16 + m16) * 264 + k * 32 + quad * 8];
            f32x4 acc[2][2];
            #pragma unroll
            for (int ri = 0; ri < 2; ++ri)
                #pragma unroll
                for (int mt = 0; mt < 2; ++mt) acc[ri][mt] = (f32x4)(0.f);
            #pragma unroll
            for (int k = 0; k < 8; ++k)
                #pragma unroll
                for (int ri = 0; ri < 2; ++ri)
                    #pragma unroll
                    for (int mt = 0; mt < 2; ++mt)
                        acc[ri][mt] = __builtin_amdgcn_mfma_f32_16x16x32_f16(
                            A[ri][mt][k], Bf[k], acc[ri][mt], 0, 0, 0);
            #pragma unroll
            for (int ri = 0; ri < 2; ++ri) {
                float p = 0.f;
                #pragma unroll
                for (int mt = 0; mt < 2; ++mt)
                    #pragma unroll
                    for (int g = 0; g < 4; ++g)
                        p += fmaxf(acc[ri][mt][g] + b2n[n], 0.f);
                p += __shfl_xor(p, 16);
                p += __shfl_xor(p, 32);
                if (quad == 0)    // zeroed diag contributed relu(b2): subtract
                    msg[(r0 + ri) * 128 + n * 16 + m16] =
                        (p - fmaxf(b2n[n], 0.f)) * (1.f / 31.f);
            }
        }
    }
}

// GRU gate GEMM: A = [msg|h|dec|0] (K=288), B = wGT[512][288]. 4 tasks/wave.
__device__ __forceinline__ void gru_gemm(const float* msg, const float* h,
                                         const float* dec4, half_t* gates,
                                         int wave, int m16, int quad) {
    half8 afr[2][9];
    #pragma unroll
    for (int mt = 0; mt < 2; ++mt) {
        const int row = mt * 16 + m16;
        #pragma unroll
        for (int k = 0; k < 4; ++k)
            afr[mt][k] = frag_from_f32(&msg[row * 128 + k * 32 + quad * 8]);
        #pragma unroll
        for (int k = 0; k < 4; ++k)
            afr[mt][4 + k] = frag_from_f32(&h[row * 128 + k * 32 + quad * 8]);
        half8 t = h8zero();
        if (quad == 0) {
            t[0] = (half_t)dec4[row * 4 + 0];
            t[1] = (half_t)dec4[row * 4 + 1];
            t[2] = (half_t)dec4[row * 4 + 2];
        }
        afr[mt][8] = t;
    }
    const half_t* Bt = g_wf16 + OFF_WGT;
    #pragma unroll
    for (int g = 0; g < 4; ++g) {
        const int nt = wave + g * 8;
        const int j = nt * 16 + m16;
        f32x4 acc[2];
        acc[0] = (f32x4)(0.f);
        acc[1] = (f32x4)(0.f);
        #pragma unroll
        for (int k = 0; k < 9; ++k) {
            const bool use = (g <= 1) || (g == 2 && (k < 4 || k == 8))
                                      || (g == 3 && k >= 4 && k < 8);
            if (use) {
                half8 bf = *(const half8*)&Bt[(nt * 16 + m16) * 288 + k * 32 + quad * 8];
                #pragma unroll
                for (int mt = 0; mt < 2; ++mt)
                    acc[mt] = __builtin_amdgcn_mfma_f32_16x16x32_f16(
                        afr[mt][k], bf, acc[mt], 0, 0, 0);
            }
        }
        #pragma unroll
        for (int mt = 0; mt < 2; ++mt)
            #pragma unroll
            for (int gg = 0; gg < 4; ++gg)
                gates[(mt * 16 + quad * 4 + gg) * 512 + j] = (half_t)acc[mt][gg];
    }
}

// GRU nonlinearity + state update + output write. thread -> (s, 8 cols).
__device__ __forceinline__ void gru_epilogue(const half_t* gates, float* h,
                                             const float* b_ir, const float* b_ii,
                                             const float* b_in, float* outp,
                                             float* out2p, int tid, int b) {
    const int s = tid >> 4;
    const int j0 = (tid & 15) * 8;
    half8 rsv = *(const half8*)&gates[s * 512 + j0];
    half8 isv = *(const half8*)&gates[s * 512 + 128 + j0];
    half8 nsv = *(const half8*)&gates[s * 512 + 256 + j0];
    half8 hnv = *(const half8*)&gates[s * 512 + 384 + j0];
    f32x4 br0 = *(const f32x4*)(b_ir + j0), br1 = *(const f32x4*)(b_ir + j0 + 4);
    f32x4 bi0 = *(const f32x4*)(b_ii + j0), bi1 = *(const f32x4*)(b_ii + j0 + 4);
    f32x4 bn0 = *(const f32x4*)(b_in + j0), bn1 = *(const f32x4*)(b_in + j0 + 4);
    float hr[8];
    #pragma unroll
    for (int e = 0; e < 8; ++e) {
        const float rs = (float)rsv[e] + ((e < 4) ? br0[e] : br1[e - 4]);
        const float is = (float)isv[e] + ((e < 4) ? bi0[e] : bi1[e - 4]);
        const float ns = (float)nsv[e] + ((e < 4) ? bn0[e] : bn1[e - 4]);
        const float hn = (float)hnv[e];
        const float r = 1.f / (1.f + __expf(-rs));
        const float ii = 1.f / (1.f + __expf(-is));
        const float n = tanhf(ns + r * hn);
        const float hv = h[s * 128 + j0 + e];
        hr[e] = (1.f - ii) * n + ii * hv;
    }
    #pragma unroll
    for (int e = 0; e < 8; ++e) h[s * 128 + j0 + e] = hr[e];
    float* op = outp + ((size_t)b * 32 + s) * 128 + j0;
    #pragma unroll
    for (int e = 0; e < 8; ++e) op[e] = hr[e];
    if (out2p) {
        float* o2 = out2p + ((size_t)b * 32 + s) * 128 + j0;
        #pragma unroll
        for (int e = 0; e < 8; ++e) o2[e] = hr[e];
    }
}

// ======================= the fused kernel =======================
__global__ void __launch_bounds__(512, 2)
gnn_kernel(const float* __restrict__ enc_in, const float* __restrict__ dec_in,
           const float* __restrict__ enc_b1, const float* __restrict__ enc_b2,
           const float* __restrict__ pe_b1, const float* __restrict__ pe_b2,
           const float* __restrict__ pn_b1, const float* __restrict__ pn_b2,
           const float* __restrict__ de_b1, const float* __restrict__ de_b2,
           const float* __restrict__ b_ir, const float* __restrict__ b_ii,
           const float* __restrict__ b_in, float* __restrict__ out) {
    const int b = blockIdx.x;
    const int tid = threadIdx.x;
    const int wave = tid >> 6;
    const int lane = tid & 63;
    const int m16 = lane & 15, quad = lane >> 4;

    __shared__ __align__(16) half_t s_w2T[128 * 264];   // 67.6 KB
    __shared__ __align__(16) half_t s_pool[16896];      // P[32][264] | Qb ; gates overlay
    __shared__ __align__(16) float s_h[32 * 128];       // 16 KB
    __shared__ __align__(16) float s_msg[32 * 128];     // 16 KB ; encin overlay
    __shared__ __align__(16) float s_dec[32 * 4];

    half_t* s_P = s_pool;
    half_t* s_Qb = s_pool + 8448;
    half_t* s_gates = s_pool;              // [32][512] (32768 <= 33792)
    half_t* s_encin = (half_t*)s_msg;      // [32][168]
    half_t* s_hid = s_P;                   // MLP hidden [32][264]

    // stage encoder input (fp16, k-padded) + load pe_w2T into LDS
    for (int i = tid; i < 32 * 168; i += 512) {
        const int s = i / 168, k = i - s * 168;
        s_encin[i] = (half_t)((k < 150) ? enc_in[((size_t)b * 32 + s) * 150 + k] : 0.f);
    }
    for (int i = tid; i < 128 * 32; i += 512) {
        const int row = i >> 5, c = i & 31;
        *(half8*)&s_w2T[row * 264 + c * 8] =
            *(const half8*)&g_wf16[OFF_PE_W2T + row * 256 + c * 8];
    }
    __syncthreads();

    // ---- encoder MLP ----
    mlp_l1<0>(s_encin, nullptr, g_wf16 + OFF_ENC_W1T, 160, 5, enc_b1, s_hid,
              wave, m16, quad);
    __syncthreads();
    mlp_l2(s_hid, g_wf16 + OFF_ENC_W2T, enc_b2, s_h, wave, m16, quad);
    __syncthreads();

    // ---- 2 message-passing rounds ----
    for (int p = 0; p < 2; ++p) {
        pq_phase(s_h, g_wf16 + OFF_PE_W1T, pe_b1, s_P, s_Qb, wave, m16, quad);
        __syncthreads();
        edge_phase(s_P, s_Qb, s_w2T, pe_b2, s_msg, wave, m16, quad);
        __syncthreads();
        mlp_l1<1>(nullptr, s_msg, g_wf16 + OFF_PN_W1T, 128, 4, pn_b1, s_hid,
                  wave, m16, quad);
        __syncthreads();
        mlp_l2(s_hid, g_wf16 + OFF_PN_W2T, pn_b2, s_h, wave, m16, quad);
        __syncthreads();
    }

    // swap LDS w2T to decoder edge weights
    for (int i = tid; i < 128 * 32; i += 512) {
        const int row = i >> 5, c = i & 31;
        *(half8*)&s_w2T[row * 264 + c * 8] =
            *(const half8*)&g_wf16[OFF_DE_W2T + row * 256 + c * 8];
    }
    __syncthreads();

    // ---- GRU decoder: 25 steps ----
    for (int t = 0; t < TSTEPS; ++t) {
        if (tid < 128) {
            const int s = tid >> 2, c = tid & 3;
            s_dec[tid] = (c < 3)
                ? dec_in[(((size_t)t * 16 + b) * 32 + s) * 3 + c] : 0.f;
        }
        pq_phase(s_h, g_wf16 + OFF_DE_W1T, de_b1, s_P, s_Qb, wave, m16, quad);
        __syncthreads();
        edge_phase(s_P, s_Qb, s_w2T, de_b2, s_msg, wave, m16, quad);
        __syncthreads();
        gru_gemm(s_msg, s_h, s_dec, s_gates, wave, m16, quad);
        __syncthreads();
        gru_epilogue(s_gates, s_h, b_ir, b_ii, b_in,
                     out + (size_t)t * ROWS * 128,
                     (t == TSTEPS - 1) ? out + (size_t)TSTEPS * ROWS * 128 : nullptr,
                     tid, b);
        __syncthreads();
    }
}

extern "C" void kernel_launch(void* const* d_in, const int* in_sizes, int n_in,
                              void* d_out, int out_size, void* d_ws, size_t ws_size,
                              hipStream_t stream) {
    const float* enc_in = (const float*)d_in[0];
    const float* dec_in = (const float*)d_in[1];
    // d_in[2], d_in[3] = R, S incidence: fully-connected, not needed.
    const float* enc_w1 = (const float*)d_in[4];
    const float* enc_b1 = (const float*)d_in[5];
    const float* enc_w2 = (const float*)d_in[6];
    const float* enc_b2 = (const float*)d_in[7];
    const float* pe_w1 = (const float*)d_in[8];
    const float* pe_b1 = (const float*)d_in[9];
    const float* pe_w2 = (const float*)d_in[10];
    const float* pe_b2 = (const float*)d_in[11];
    const float* pn_w1 = (const float*)d_in[12];
    const float* pn_b1 = (const float*)d_in[13];
    const float* pn_w2 = (const float*)d_in[14];
    const float* pn_b2 = (const float*)d_in[15];
    const float* de_w1 = (const float*)d_in[16];
    const float* de_b1 = (const float*)d_in[17];
    const float* de_w2 = (const float*)d_in[18];
    const float* de_b2 = (const float*)d_in[19];
    const float* w_hr = (const float*)d_in[20];
    const float* w_hi = (const float*)d_in[21];
    const float* w_hn = (const float*)d_in[22];
    const float* w_ir = (const float*)d_in[23];
    const float* b_ir = (const float*)d_in[24];
    const float* w_ii = (const float*)d_in[25];
    const float* b_ii = (const float*)d_in[26];
    const float* w_in = (const float*)d_in[27];
    const float* b_in = (const float*)d_in[28];
    (void)d_ws; (void)ws_size; (void)in_sizes; (void)n_in;

    convert_kernel<<<(WTOTAL + 255) / 256, 256, 0, stream>>>(
        enc_w1, enc_w2, pe_w1, pe_w2, pn_w1, pn_w2, de_w1, de_w2,
        w_hr, w_hi, w_hn, w_ir, w_ii, w_in);

    gnn_kernel<<<16, 512, 0, stream>>>(
        enc_in, dec_in, enc_b1, enc_b2, pe_b1, pe_b2, pn_b1, pn_b2,
        de_b1, de_b2, b_ir, b_ii, b_in, (float*)d_out);
}